// Round 10
// baseline (288.131 us; speedup 1.0000x reference)
//
#include <hip/hip_runtime.h>
#include <hip/hip_bf16.h>

#define C_IN 128
#define C_OUT 32
#define BSH 8               // 256 nodes per dst-bucket
#define BSZ 256             // nodes per bucket
#define CH 8192             // edges per bin block
#define MAXNB 512           // LDS cap for bucket arrays (supports n <= 131072)
#define TR 64               // gemm row-tile

static __device__ __forceinline__ unsigned short f2bf(float f) {
    __hip_bfloat16 h = __float2bfloat16(f);   // RTNE
    return *reinterpret_cast<unsigned short*>(&h);
}
static __device__ __forceinline__ float bf2f(unsigned short u) {
    unsigned int v = ((unsigned int)u) << 16;
    return __uint_as_float(v);
}

// ================= bucket histogram =================
__global__ __launch_bounds__(256) void bucket_hist_kernel(const int* __restrict__ dst, int E,
                                                          int* __restrict__ bcnt, int nb) {
    __shared__ int hcnt[MAXNB];
    for (int i = threadIdx.x; i < nb; i += 256) hcnt[i] = 0;
    __syncthreads();
    int stride = gridDim.x * 256;
    for (int e = blockIdx.x * 256 + threadIdx.x; e < E; e += stride)
        atomicAdd(&hcnt[dst[e] >> BSH], 1);
    __syncthreads();
    for (int i = threadIdx.x; i < nb; i += 256)
        if (hcnt[i]) atomicAdd(&bcnt[i], hcnt[i]);
}

// ================= bucket exclusive scan (1 block) =================
__global__ __launch_bounds__(512) void bucket_scan_kernel(const int* __restrict__ bcnt,
                                                          int* __restrict__ bbase,
                                                          int* __restrict__ gcur, int nb, int E) {
    __shared__ int tmp[512];
    int v = (threadIdx.x < nb) ? bcnt[threadIdx.x] : 0;
    tmp[threadIdx.x] = v;
    __syncthreads();
    for (int off = 1; off < 512; off <<= 1) {
        int t = (threadIdx.x >= off) ? tmp[threadIdx.x - off] : 0;
        __syncthreads();
        tmp[threadIdx.x] += t;
        __syncthreads();
    }
    if (threadIdx.x < nb) {
        int ex = tmp[threadIdx.x] - v;
        bbase[threadIdx.x] = ex;
        gcur[threadIdx.x] = ex;
    }
    if (threadIdx.x == 0) bbase[nb] = E;
}

// ================= bin edges into bucket-grouped packed (src<<8 | dst&255) =================
__global__ __launch_bounds__(256) void bin_kernel(const int* __restrict__ src,
                                                  const int* __restrict__ dst, int E,
                                                  int* __restrict__ gcur,
                                                  unsigned int* __restrict__ pk, int nb) {
    __shared__ int lcnt[MAXNB];
    __shared__ int lbase[MAXNB];
    int e0 = blockIdx.x * CH;
    for (int i = threadIdx.x; i < nb; i += 256) lcnt[i] = 0;
    __syncthreads();
    for (int i = threadIdx.x; i < CH; i += 256) {
        int e = e0 + i;
        if (e < E) atomicAdd(&lcnt[dst[e] >> BSH], 1);
    }
    __syncthreads();
    for (int i = threadIdx.x; i < nb; i += 256) {
        int c = lcnt[i];
        lbase[i] = c ? atomicAdd(&gcur[i], c) : 0;
        lcnt[i] = 0;
    }
    __syncthreads();
    for (int i = threadIdx.x; i < CH; i += 256) {
        int e = e0 + i;
        if (e < E) {
            int d = dst[e], s = src[e];
            int b = d >> BSH;
            int off = atomicAdd(&lcnt[b], 1);
            pk[lbase[b] + off] = ((unsigned int)s << BSH) | (unsigned int)(d & (BSZ - 1));
        }
    }
}

// ================= per-bucket counting sort -> full CSR + dinv =================
__global__ __launch_bounds__(256) void csr_build_kernel(const unsigned int* __restrict__ pk,
                                                        const int* __restrict__ bbase,
                                                        int* __restrict__ ptr,
                                                        int* __restrict__ srcs,
                                                        float* __restrict__ dinv, int n, int E) {
    __shared__ int cnt[BSZ];
    __shared__ int tmp[BSZ];
    __shared__ int cur[BSZ];
    int b = blockIdx.x;
    int tid = threadIdx.x;
    int r0 = bbase[b], r1 = bbase[b + 1];
    cnt[tid] = 0;
    __syncthreads();
    for (int i = r0 + tid; i < r1; i += 256)
        atomicAdd(&cnt[pk[i] & (BSZ - 1)], 1);
    __syncthreads();
    int v = cnt[tid];
    tmp[tid] = v;
    __syncthreads();
    for (int off = 1; off < 256; off <<= 1) {
        int t = (tid >= off) ? tmp[tid - off] : 0;
        __syncthreads();
        tmp[tid] += t;
        __syncthreads();
    }
    int ex = tmp[tid] - v;  // exclusive offset within bucket
    cur[tid] = ex;
    int node = (b << BSH) + tid;
    if (node < n) {
        ptr[node] = r0 + ex;
        dinv[node] = rsqrtf((float)(v + 1));  // +1 self loop
    }
    if (b == 0 && tid == 0) ptr[n] = E;
    __syncthreads();
    for (int i = r0 + tid; i < r1; i += 256) {
        unsigned int u = pk[i];
        int d = u & (BSZ - 1);
        int pos = r0 + atomicAdd(&cur[d], 1);
        srcs[pos] = (int)(u >> BSH);
    }
}

// 4 chained FMAs: acc.comp += dot(xv, W[k..k+3][c_comp])
#define FMA4(acc, xv, comp)                           \
    acc.comp = fmaf(xv.x, w0.comp, acc.comp);         \
    acc.comp = fmaf(xv.y, w1.comp, acc.comp);         \
    acc.comp = fmaf(xv.z, w2.comp, acc.comp);         \
    acc.comp = fmaf(xv.w, w3.comp, acc.comp);

// split-half bf16 store: channels [0,16) -> hwA, [16,32) -> hwB (separate 3.2 MB arrays
// so each aggregate_half dispatch's working set fits a 4 MB per-XCD L2)
static __device__ __forceinline__ void store_half(unsigned short* hwA, unsigned short* hwB,
                                                  int row, int c0, float4 a, float dv) {
    ushort4 o;
    o.x = f2bf(a.x * dv); o.y = f2bf(a.y * dv);
    o.z = f2bf(a.z * dv); o.w = f2bf(a.w * dv);
    unsigned short* base = (c0 < 16) ? &hwA[(size_t)row * 16 + c0]
                                     : &hwB[(size_t)row * 16 + (c0 - 16)];
    *((ushort4*)base) = o;
}

// ================= GEMM1 (tiled) + dinv fold -> split bf16 halves =================
// unroll capped at 2 (R5: full unroll -> 256 VGPR + scratch spill). 3 blk/CU.
__global__ __launch_bounds__(256, 3) void gemm1_kernel(const float* __restrict__ x,
                                                       const float* __restrict__ W,
                                                       const float* __restrict__ dinv,
                                                       unsigned short* __restrict__ hwA,
                                                       unsigned short* __restrict__ hwB, int n) {
    __shared__ float xs[TR][C_IN + 4];   // 64 x 132 = 33 KB (pad -> 2-way max aliasing)
    __shared__ float Ws[C_IN * C_OUT];   // 16 KB
    int tid = threadIdx.x;
    for (int i = tid; i < (C_IN * C_OUT) / 4; i += 256)
        ((float4*)Ws)[i] = ((const float4*)W)[i];
    int row0 = blockIdx.x * TR;
    for (int i = tid; i < TR * (C_IN / 4); i += 256) {
        int r = i >> 5, k4 = i & 31;
        int row = row0 + r;
        float4 v = make_float4(0.f, 0.f, 0.f, 0.f);
        if (row < n) v = ((const float4*)(x + (size_t)row * C_IN))[k4];
        *((float4*)&xs[r][k4 * 4]) = v;
    }
    __syncthreads();

    int rp = tid >> 3;          // 0..31 -> rows 2rp, 2rp+1
    int c0 = (tid & 7) * 4;     // channel group
    int r0 = rp * 2, r1 = r0 + 1;
    float4 acc0 = make_float4(0.f, 0.f, 0.f, 0.f);
    float4 acc1 = make_float4(0.f, 0.f, 0.f, 0.f);
#pragma unroll 2
    for (int k4 = 0; k4 < C_IN / 4; ++k4) {
        float4 xa = *((const float4*)&xs[r0][k4 * 4]);
        float4 xb = *((const float4*)&xs[r1][k4 * 4]);
        float4 w0 = *((const float4*)&Ws[(k4 * 4 + 0) * C_OUT + c0]);
        float4 w1 = *((const float4*)&Ws[(k4 * 4 + 1) * C_OUT + c0]);
        float4 w2 = *((const float4*)&Ws[(k4 * 4 + 2) * C_OUT + c0]);
        float4 w3 = *((const float4*)&Ws[(k4 * 4 + 3) * C_OUT + c0]);
        FMA4(acc0, xa, x) FMA4(acc0, xa, y) FMA4(acc0, xa, z) FMA4(acc0, xa, w)
        FMA4(acc1, xb, x) FMA4(acc1, xb, y) FMA4(acc1, xb, z) FMA4(acc1, xb, w)
    }
    int rowA = row0 + r0;
    if (rowA < n) store_half(hwA, hwB, rowA, c0, acc0, dinv[rowA]);
    int rowB = row0 + r1;
    if (rowB < n) store_half(hwA, hwB, rowB, c0, acc1, dinv[rowB]);
}

// ================= GEMM2 (tiled) + relu on load + dinv fold -> split bf16 halves =================
__global__ __launch_bounds__(256, 4) void gemm2_relu_kernel(const float* __restrict__ a,
                                                            const float* __restrict__ W,
                                                            const float* __restrict__ dinv,
                                                            unsigned short* __restrict__ hwA,
                                                            unsigned short* __restrict__ hwB, int n) {
    __shared__ float xs[TR][C_OUT + 4];  // 64 x 36 = 9 KB
    __shared__ float Ws[C_OUT * C_OUT];  // 4 KB
    int tid = threadIdx.x;
    for (int i = tid; i < (C_OUT * C_OUT) / 4; i += 256)
        ((float4*)Ws)[i] = ((const float4*)W)[i];
    int row0 = blockIdx.x * TR;
    for (int i = tid; i < TR * (C_OUT / 4); i += 256) {
        int r = i >> 3, k4 = i & 7;
        int row = row0 + r;
        float4 v = make_float4(0.f, 0.f, 0.f, 0.f);
        if (row < n) {
            v = ((const float4*)(a + (size_t)row * C_OUT))[k4];
            v.x = fmaxf(v.x, 0.f); v.y = fmaxf(v.y, 0.f);
            v.z = fmaxf(v.z, 0.f); v.w = fmaxf(v.w, 0.f);
        }
        *((float4*)&xs[r][k4 * 4]) = v;
    }
    __syncthreads();

    int rp = tid >> 3;
    int c0 = (tid & 7) * 4;
    int r0 = rp * 2, r1 = r0 + 1;
    float4 acc0 = make_float4(0.f, 0.f, 0.f, 0.f);
    float4 acc1 = make_float4(0.f, 0.f, 0.f, 0.f);
#pragma unroll 2
    for (int k4 = 0; k4 < C_OUT / 4; ++k4) {
        float4 xa = *((const float4*)&xs[r0][k4 * 4]);
        float4 xb = *((const float4*)&xs[r1][k4 * 4]);
        float4 w0 = *((const float4*)&Ws[(k4 * 4 + 0) * C_OUT + c0]);
        float4 w1 = *((const float4*)&Ws[(k4 * 4 + 1) * C_OUT + c0]);
        float4 w2 = *((const float4*)&Ws[(k4 * 4 + 2) * C_OUT + c0]);
        float4 w3 = *((const float4*)&Ws[(k4 * 4 + 3) * C_OUT + c0]);
        FMA4(acc0, xa, x) FMA4(acc0, xa, y) FMA4(acc0, xa, z) FMA4(acc0, xa, w)
        FMA4(acc1, xb, x) FMA4(acc1, xb, y) FMA4(acc1, xb, z) FMA4(acc1, xb, w)
    }
    int rowA = row0 + r0;
    if (rowA < n) store_half(hwA, hwB, rowA, c0, acc0, dinv[rowA]);
    int rowB = row0 + r1;
    if (rowB < n) store_half(hwA, hwB, rowB, c0, acc1, dinv[rowB]);
}

// ================= per-node wave gather over ONE channel half =================
// hwh: [n][16] bf16 (3.2 MB -> L2-resident per XCD). 16 lanes/row, 4 rows/instr.
// out[v, ch0+c] = dinv[v] * (sum_s hwh[s,c] + hwh[v,c]) + bias[ch0+c]
// HAZARD (R7): __shfl from an exec-masked-off lane is UNDEFINED -> every __shfl runs
// with all 64 lanes active (uniform jend loop); only dependent adds are predicated.
// Streaming data (ptr/srcs/out) uses nontemporal ops so it doesn't evict hwh from L2.
__global__ __launch_bounds__(256) void aggregate_half_kernel(const unsigned short* __restrict__ hwh,
                                                             const float* __restrict__ dinv,
                                                             const int* __restrict__ ptr,
                                                             const int* __restrict__ srcs,
                                                             const float* __restrict__ bias,
                                                             int ch0,
                                                             float* __restrict__ out, int n) {
    int wid = (blockIdx.x * 256 + threadIdx.x) >> 6;  // node = global wave id
    if (wid >= n) return;                             // wave-uniform
    int lane = threadIdx.x & 63;
    int r = lane >> 4;     // row slot 0..3
    int c = lane & 15;     // channel within half
    int beg = __builtin_nontemporal_load(&ptr[wid]);
    int end = __builtin_nontemporal_load(&ptr[wid + 1]);
    int deg = end - beg;
    int sv = (beg + lane < end) ? __builtin_nontemporal_load(&srcs[beg + lane]) : 0;
    int jend = deg < 64 ? deg : 64;                   // wave-uniform
    float a0 = 0.f, a1 = 0.f, a2 = 0.f, a3 = 0.f;
    for (int jb = 0; jb < jend; jb += 16) {           // uniform trips; 16 edges/iter
        int j0 = jb + r;
        int s0 = __shfl(sv, j0);
        int s1 = __shfl(sv, j0 + 4);
        int s2 = __shfl(sv, j0 + 8);
        int s3 = __shfl(sv, j0 + 12);
        if (j0 < jend)      a0 += bf2f(hwh[(size_t)s0 * 16 + c]);
        if (j0 + 4 < jend)  a1 += bf2f(hwh[(size_t)s1 * 16 + c]);
        if (j0 + 8 < jend)  a2 += bf2f(hwh[(size_t)s2 * 16 + c]);
        if (j0 + 12 < jend) a3 += bf2f(hwh[(size_t)s3 * 16 + c]);
    }
    // rare overflow: degree > 64 (row slot r handles every 4th extra edge)
    for (int e = beg + 64 + r; e < end; e += 4)
        a0 += bf2f(hwh[(size_t)__builtin_nontemporal_load(&srcs[e]) * 16 + c]);
    float acc = (a0 + a1) + (a2 + a3);
    acc += __shfl_xor(acc, 16);  // sum across row slots (all lanes active)
    acc += __shfl_xor(acc, 32);
    if (lane < 16) {
        float dv = dinv[wid];
        float v = dv * (acc + bf2f(hwh[(size_t)wid * 16 + c])) + bias[ch0 + c];
        __builtin_nontemporal_store(v, &out[(size_t)wid * C_OUT + ch0 + c]);
    }
}

// ================= fallback (R1 atomic path) =================
__global__ void count_deg_kernel(const int* __restrict__ dst, int E, int* __restrict__ cnt) {
    int i = blockIdx.x * blockDim.x + threadIdx.x;
    if (i < E) atomicAdd(&cnt[dst[i]], 1);
}

__global__ void dinv_from_cnt_kernel(const int* __restrict__ cnt, float* __restrict__ dinv, int n) {
    int i = blockIdx.x * blockDim.x + threadIdx.x;
    if (i < n) dinv[i] = rsqrtf((float)(cnt[i] + 1));
}

__global__ void selfloop_bias_kernel(const float* __restrict__ h, const float* __restrict__ dinv,
                                     const float* __restrict__ b, float* __restrict__ out, int n) {
    int t = blockIdx.x * blockDim.x + threadIdx.x;
    if (t >= n * C_OUT) return;
    int i = t >> 5;
    int c = t & 31;
    float di = dinv[i];
    out[t] = h[t] * di * di + b[c];
}

__global__ void scatter_kernel(const int* __restrict__ src, const int* __restrict__ dst, int E,
                               const float* __restrict__ dinv, const float* __restrict__ h,
                               float* __restrict__ out) {
    int t = blockIdx.x * blockDim.x + threadIdx.x;
    int e = t >> 5;
    if (e >= E) return;
    int c = t & 31;
    int s = src[e];
    int d = dst[e];
    float norm = dinv[s] * dinv[d];
    float v = h[(size_t)s * C_OUT + c] * norm;
    atomicAdd(&out[(size_t)d * C_OUT + c], v);
}

// plain gemm (no dinv fold) for fallback
__global__ __launch_bounds__(256) void gemm1_plain_kernel(const float* __restrict__ x,
                                                          const float* __restrict__ W,
                                                          float* __restrict__ h, int n) {
    __shared__ float Ws[C_IN * C_OUT];
    for (int i = threadIdx.x; i < (C_IN * C_OUT) / 4; i += 256)
        ((float4*)Ws)[i] = ((const float4*)W)[i];
    __syncthreads();
    int t = blockIdx.x * 256 + threadIdx.x;
    int row = t >> 5;
    if (row >= n) return;
    int c = t & 31;
    const float4* xr = (const float4*)(x + (size_t)row * C_IN);
    float acc = 0.f;
#pragma unroll
    for (int k4 = 0; k4 < C_IN / 4; ++k4) {
        float4 xv = xr[k4];
        acc = fmaf(xv.x, Ws[(k4 * 4 + 0) * C_OUT + c], acc);
        acc = fmaf(xv.y, Ws[(k4 * 4 + 1) * C_OUT + c], acc);
        acc = fmaf(xv.z, Ws[(k4 * 4 + 2) * C_OUT + c], acc);
        acc = fmaf(xv.w, Ws[(k4 * 4 + 3) * C_OUT + c], acc);
    }
    h[(size_t)row * C_OUT + c] = acc;
}

__global__ __launch_bounds__(256) void gemm2_relu_plain_kernel(const float* __restrict__ a,
                                                               const float* __restrict__ W,
                                                               float* __restrict__ h, int n) {
    __shared__ float Ws[C_OUT * C_OUT];
    for (int i = threadIdx.x; i < (C_OUT * C_OUT) / 4; i += 256)
        ((float4*)Ws)[i] = ((const float4*)W)[i];
    __syncthreads();
    int t = blockIdx.x * 256 + threadIdx.x;
    int row = t >> 5;
    if (row >= n) return;
    int c = t & 31;
    const float4* ar = (const float4*)(a + (size_t)row * C_OUT);
    float acc = 0.f;
#pragma unroll
    for (int k4 = 0; k4 < C_OUT / 4; ++k4) {
        float4 av = ar[k4];
        acc = fmaf(fmaxf(av.x, 0.f), Ws[(k4 * 4 + 0) * C_OUT + c], acc);
        acc = fmaf(fmaxf(av.y, 0.f), Ws[(k4 * 4 + 1) * C_OUT + c], acc);
        acc = fmaf(fmaxf(av.z, 0.f), Ws[(k4 * 4 + 2) * C_OUT + c], acc);
        acc = fmaf(fmaxf(av.w, 0.f), Ws[(k4 * 4 + 3) * C_OUT + c], acc);
    }
    h[(size_t)row * C_OUT + c] = acc;
}

extern "C" void kernel_launch(void* const* d_in, const int* in_sizes, int n_in,
                              void* d_out, int out_size, void* d_ws, size_t ws_size,
                              hipStream_t stream) {
    const float* x  = (const float*)d_in[0];
    const int*   ei = (const int*)d_in[1];
    const float* W1 = (const float*)d_in[2];
    const float* b1 = (const float*)d_in[3];
    const float* W2 = (const float*)d_in[4];
    const float* b2 = (const float*)d_in[5];

    const int n = in_sizes[0] / C_IN;   // 100000
    const int E = in_sizes[1] / 2;      // 1600000
    const int* src = ei;
    const int* dst = ei + E;
    float* aout = (float*)d_out;

    const int nb = (n + BSZ - 1) >> BSH;            // 391
    const size_t MB = 1024 * 1024;
    char* ws = (char*)d_ws;

    size_t need = 20 * MB + (size_t)n * 16 * sizeof(unsigned short);

    if (ws_size >= need && n <= (MAXNB << BSH) && n < (1 << 24)) {
        int*            bcnt  = (int*)(ws + 0);
        int*            bbase = (int*)(ws + 64 * 1024);
        int*            gcur  = (int*)(ws + 128 * 1024);
        float*          dinv  = (float*)(ws + 192 * 1024);
        int*            ptr   = (int*)(ws + 704 * 1024);
        unsigned int*   pk    = (unsigned int*)(ws + 2 * MB);
        int*            srcs  = (int*)(ws + 9 * MB);
        unsigned short* hwA   = (unsigned short*)(ws + 16 * MB);  // n*16 bf16 = 3.2 MB
        unsigned short* hwB   = (unsigned short*)(ws + 20 * MB);  // n*16 bf16 = 3.2 MB

        // ---- build bucket-grouped pairs, then per-node CSR ----
        hipMemsetAsync(bcnt, 0, (size_t)(nb + 1) * sizeof(int), stream);
        bucket_hist_kernel<<<512, 256, 0, stream>>>(dst, E, bcnt, nb);
        bucket_scan_kernel<<<1, 512, 0, stream>>>(bcnt, bbase, gcur, nb, E);
        bin_kernel<<<(E + CH - 1) / CH, 256, 0, stream>>>(src, dst, E, gcur, pk, nb);
        csr_build_kernel<<<nb, 256, 0, stream>>>(pk, bbase, ptr, srcs, dinv, n, E);

        const int gb = (n + TR - 1) / TR;                 // 1563
        const int ga = ((size_t)n * 64 + 255) / 256;      // aggregate grid
        // ---- layer 1 ----
        gemm1_kernel<<<gb, 256, 0, stream>>>(x, W1, dinv, hwA, hwB, n);
        aggregate_half_kernel<<<ga, 256, 0, stream>>>(hwA, dinv, ptr, srcs, b1, 0,  aout, n);
        aggregate_half_kernel<<<ga, 256, 0, stream>>>(hwB, dinv, ptr, srcs, b1, 16, aout, n);
        // ---- layer 2 ----
        gemm2_relu_kernel<<<gb, 256, 0, stream>>>(aout, W2, dinv, hwA, hwB, n);
        aggregate_half_kernel<<<ga, 256, 0, stream>>>(hwA, dinv, ptr, srcs, b2, 0,  aout, n);
        aggregate_half_kernel<<<ga, 256, 0, stream>>>(hwB, dinv, ptr, srcs, b2, 16, aout, n);
    } else {
        // -------- fallback: R1 atomic path (needs ~13.6 MB) --------
        int*   cnt  = (int*)ws;
        float* dinv = (float*)(ws + 400000);
        float* h    = (float*)(ws + 800000);

        hipMemsetAsync(cnt, 0, (size_t)n * sizeof(int), stream);
        count_deg_kernel<<<(E + 255) / 256, 256, 0, stream>>>(dst, E, cnt);
        gemm1_plain_kernel<<<(n * C_OUT + 255) / 256, 256, 0, stream>>>(x, W1, h, n);
        dinv_from_cnt_kernel<<<(n + 255) / 256, 256, 0, stream>>>(cnt, dinv, n);
        selfloop_bias_kernel<<<(n * C_OUT + 255) / 256, 256, 0, stream>>>(h, dinv, b1, aout, n);
        scatter_kernel<<<((size_t)E * 32 + 255) / 256, 256, 0, stream>>>(src, dst, E, dinv, h, aout);
        gemm2_relu_plain_kernel<<<(n * C_OUT + 255) / 256, 256, 0, stream>>>(aout, W2, h, n);
        selfloop_bias_kernel<<<(n * C_OUT + 255) / 256, 256, 0, stream>>>(h, dinv, b2, aout, n);
        scatter_kernel<<<((size_t)E * 32 + 255) / 256, 256, 0, stream>>>(src, dst, E, dinv, h, aout);
    }
}

// Round 11
// 172.708 us; speedup vs baseline: 1.6683x; 1.6683x over previous
//
#include <hip/hip_runtime.h>
#include <hip/hip_bf16.h>

#define C_IN 128
#define C_OUT 32
#define BSH 8               // 256 nodes per dst-bucket
#define BSZ 256             // nodes per bucket
#define CH 8192             // edges per bin block
#define MAXNB 512           // LDS cap for bucket arrays (supports n <= 131072)
#define TR 64               // gemm row-tile
#define NPB 16              // nodes per aggregate block
#define ECAP 1024           // LDS-staged edges per aggregate block (avg 256, P(>1024)~0)

static __device__ __forceinline__ unsigned short f2bf(float f) {
    __hip_bfloat16 h = __float2bfloat16(f);   // RTNE
    return *reinterpret_cast<unsigned short*>(&h);
}
static __device__ __forceinline__ float bf2f(unsigned short u) {
    unsigned int v = ((unsigned int)u) << 16;
    return __uint_as_float(v);
}

// ================= bucket histogram =================
__global__ __launch_bounds__(256) void bucket_hist_kernel(const int* __restrict__ dst, int E,
                                                          int* __restrict__ bcnt, int nb) {
    __shared__ int hcnt[MAXNB];
    for (int i = threadIdx.x; i < nb; i += 256) hcnt[i] = 0;
    __syncthreads();
    int stride = gridDim.x * 256;
    for (int e = blockIdx.x * 256 + threadIdx.x; e < E; e += stride)
        atomicAdd(&hcnt[dst[e] >> BSH], 1);
    __syncthreads();
    for (int i = threadIdx.x; i < nb; i += 256)
        if (hcnt[i]) atomicAdd(&bcnt[i], hcnt[i]);
}

// ================= bucket exclusive scan (1 block) =================
__global__ __launch_bounds__(512) void bucket_scan_kernel(const int* __restrict__ bcnt,
                                                          int* __restrict__ bbase,
                                                          int* __restrict__ gcur, int nb, int E) {
    __shared__ int tmp[512];
    int v = (threadIdx.x < nb) ? bcnt[threadIdx.x] : 0;
    tmp[threadIdx.x] = v;
    __syncthreads();
    for (int off = 1; off < 512; off <<= 1) {
        int t = (threadIdx.x >= off) ? tmp[threadIdx.x - off] : 0;
        __syncthreads();
        tmp[threadIdx.x] += t;
        __syncthreads();
    }
    if (threadIdx.x < nb) {
        int ex = tmp[threadIdx.x] - v;
        bbase[threadIdx.x] = ex;
        gcur[threadIdx.x] = ex;
    }
    if (threadIdx.x == 0) bbase[nb] = E;
}

// ================= bin edges into bucket-grouped packed (src<<8 | dst&255) =================
__global__ __launch_bounds__(256) void bin_kernel(const int* __restrict__ src,
                                                  const int* __restrict__ dst, int E,
                                                  int* __restrict__ gcur,
                                                  unsigned int* __restrict__ pk, int nb) {
    __shared__ int lcnt[MAXNB];
    __shared__ int lbase[MAXNB];
    int e0 = blockIdx.x * CH;
    for (int i = threadIdx.x; i < nb; i += 256) lcnt[i] = 0;
    __syncthreads();
    for (int i = threadIdx.x; i < CH; i += 256) {
        int e = e0 + i;
        if (e < E) atomicAdd(&lcnt[dst[e] >> BSH], 1);
    }
    __syncthreads();
    for (int i = threadIdx.x; i < nb; i += 256) {
        int c = lcnt[i];
        lbase[i] = c ? atomicAdd(&gcur[i], c) : 0;
        lcnt[i] = 0;
    }
    __syncthreads();
    for (int i = threadIdx.x; i < CH; i += 256) {
        int e = e0 + i;
        if (e < E) {
            int d = dst[e], s = src[e];
            int b = d >> BSH;
            int off = atomicAdd(&lcnt[b], 1);
            pk[lbase[b] + off] = ((unsigned int)s << BSH) | (unsigned int)(d & (BSZ - 1));
        }
    }
}

// ================= per-bucket counting sort -> full CSR + dinv =================
__global__ __launch_bounds__(256) void csr_build_kernel(const unsigned int* __restrict__ pk,
                                                        const int* __restrict__ bbase,
                                                        int* __restrict__ ptr,
                                                        int* __restrict__ srcs,
                                                        float* __restrict__ dinv, int n, int E) {
    __shared__ int cnt[BSZ];
    __shared__ int tmp[BSZ];
    __shared__ int cur[BSZ];
    int b = blockIdx.x;
    int tid = threadIdx.x;
    int r0 = bbase[b], r1 = bbase[b + 1];
    cnt[tid] = 0;
    __syncthreads();
    for (int i = r0 + tid; i < r1; i += 256)
        atomicAdd(&cnt[pk[i] & (BSZ - 1)], 1);
    __syncthreads();
    int v = cnt[tid];
    tmp[tid] = v;
    __syncthreads();
    for (int off = 1; off < 256; off <<= 1) {
        int t = (tid >= off) ? tmp[tid - off] : 0;
        __syncthreads();
        tmp[tid] += t;
        __syncthreads();
    }
    int ex = tmp[tid] - v;  // exclusive offset within bucket
    cur[tid] = ex;
    int node = (b << BSH) + tid;
    if (node < n) {
        ptr[node] = r0 + ex;
        dinv[node] = rsqrtf((float)(v + 1));  // +1 self loop
    }
    if (b == 0 && tid == 0) ptr[n] = E;
    __syncthreads();
    for (int i = r0 + tid; i < r1; i += 256) {
        unsigned int u = pk[i];
        int d = u & (BSZ - 1);
        int pos = r0 + atomicAdd(&cur[d], 1);
        srcs[pos] = (int)(u >> BSH);
    }
}

// 4 chained FMAs: acc.comp += dot(xv, W[k..k+3][c_comp])
#define FMA4(acc, xv, comp)                           \
    acc.comp = fmaf(xv.x, w0.comp, acc.comp);         \
    acc.comp = fmaf(xv.y, w1.comp, acc.comp);         \
    acc.comp = fmaf(xv.z, w2.comp, acc.comp);         \
    acc.comp = fmaf(xv.w, w3.comp, acc.comp);

// ================= GEMM1 (tiled) + dinv fold: hw16 = bf16((x @ W1) * dinv[row]) =================
// unroll capped at 2 (R5: full unroll -> 256 VGPR + scratch spill). 3 blk/CU.
__global__ __launch_bounds__(256, 3) void gemm1_kernel(const float* __restrict__ x,
                                                       const float* __restrict__ W,
                                                       const float* __restrict__ dinv,
                                                       unsigned short* __restrict__ hw16, int n) {
    __shared__ float xs[TR][C_IN + 4];   // 64 x 132 = 33 KB (pad -> 2-way max aliasing)
    __shared__ float Ws[C_IN * C_OUT];   // 16 KB
    int tid = threadIdx.x;
    for (int i = tid; i < (C_IN * C_OUT) / 4; i += 256)
        ((float4*)Ws)[i] = ((const float4*)W)[i];
    int row0 = blockIdx.x * TR;
    for (int i = tid; i < TR * (C_IN / 4); i += 256) {
        int r = i >> 5, k4 = i & 31;
        int row = row0 + r;
        float4 v = make_float4(0.f, 0.f, 0.f, 0.f);
        if (row < n) v = ((const float4*)(x + (size_t)row * C_IN))[k4];
        *((float4*)&xs[r][k4 * 4]) = v;
    }
    __syncthreads();

    int rp = tid >> 3;          // 0..31 -> rows 2rp, 2rp+1
    int c0 = (tid & 7) * 4;     // channel group
    int r0 = rp * 2, r1 = r0 + 1;
    float4 acc0 = make_float4(0.f, 0.f, 0.f, 0.f);
    float4 acc1 = make_float4(0.f, 0.f, 0.f, 0.f);
#pragma unroll 2
    for (int k4 = 0; k4 < C_IN / 4; ++k4) {
        float4 xa = *((const float4*)&xs[r0][k4 * 4]);
        float4 xb = *((const float4*)&xs[r1][k4 * 4]);
        float4 w0 = *((const float4*)&Ws[(k4 * 4 + 0) * C_OUT + c0]);
        float4 w1 = *((const float4*)&Ws[(k4 * 4 + 1) * C_OUT + c0]);
        float4 w2 = *((const float4*)&Ws[(k4 * 4 + 2) * C_OUT + c0]);
        float4 w3 = *((const float4*)&Ws[(k4 * 4 + 3) * C_OUT + c0]);
        FMA4(acc0, xa, x) FMA4(acc0, xa, y) FMA4(acc0, xa, z) FMA4(acc0, xa, w)
        FMA4(acc1, xb, x) FMA4(acc1, xb, y) FMA4(acc1, xb, z) FMA4(acc1, xb, w)
    }
    int rowA = row0 + r0;
    if (rowA < n) {
        float dv = dinv[rowA];
        ushort4 o;
        o.x = f2bf(acc0.x * dv); o.y = f2bf(acc0.y * dv);
        o.z = f2bf(acc0.z * dv); o.w = f2bf(acc0.w * dv);
        *((ushort4*)&hw16[(size_t)rowA * C_OUT + c0]) = o;
    }
    int rowB = row0 + r1;
    if (rowB < n) {
        float dv = dinv[rowB];
        ushort4 o;
        o.x = f2bf(acc1.x * dv); o.y = f2bf(acc1.y * dv);
        o.z = f2bf(acc1.z * dv); o.w = f2bf(acc1.w * dv);
        *((ushort4*)&hw16[(size_t)rowB * C_OUT + c0]) = o;
    }
}

// ================= GEMM2 (tiled) + relu on load + dinv fold -> bf16 =================
__global__ __launch_bounds__(256, 4) void gemm2_relu_kernel(const float* __restrict__ a,
                                                            const float* __restrict__ W,
                                                            const float* __restrict__ dinv,
                                                            unsigned short* __restrict__ hw16, int n) {
    __shared__ float xs[TR][C_OUT + 4];  // 64 x 36 = 9 KB
    __shared__ float Ws[C_OUT * C_OUT];  // 4 KB
    int tid = threadIdx.x;
    for (int i = tid; i < (C_OUT * C_OUT) / 4; i += 256)
        ((float4*)Ws)[i] = ((const float4*)W)[i];
    int row0 = blockIdx.x * TR;
    for (int i = tid; i < TR * (C_OUT / 4); i += 256) {
        int r = i >> 3, k4 = i & 7;
        int row = row0 + r;
        float4 v = make_float4(0.f, 0.f, 0.f, 0.f);
        if (row < n) {
            v = ((const float4*)(a + (size_t)row * C_OUT))[k4];
            v.x = fmaxf(v.x, 0.f); v.y = fmaxf(v.y, 0.f);
            v.z = fmaxf(v.z, 0.f); v.w = fmaxf(v.w, 0.f);
        }
        *((float4*)&xs[r][k4 * 4]) = v;
    }
    __syncthreads();

    int rp = tid >> 3;
    int c0 = (tid & 7) * 4;
    int r0 = rp * 2, r1 = r0 + 1;
    float4 acc0 = make_float4(0.f, 0.f, 0.f, 0.f);
    float4 acc1 = make_float4(0.f, 0.f, 0.f, 0.f);
#pragma unroll 2
    for (int k4 = 0; k4 < C_OUT / 4; ++k4) {
        float4 xa = *((const float4*)&xs[r0][k4 * 4]);
        float4 xb = *((const float4*)&xs[r1][k4 * 4]);
        float4 w0 = *((const float4*)&Ws[(k4 * 4 + 0) * C_OUT + c0]);
        float4 w1 = *((const float4*)&Ws[(k4 * 4 + 1) * C_OUT + c0]);
        float4 w2 = *((const float4*)&Ws[(k4 * 4 + 2) * C_OUT + c0]);
        float4 w3 = *((const float4*)&Ws[(k4 * 4 + 3) * C_OUT + c0]);
        FMA4(acc0, xa, x) FMA4(acc0, xa, y) FMA4(acc0, xa, z) FMA4(acc0, xa, w)
        FMA4(acc1, xb, x) FMA4(acc1, xb, y) FMA4(acc1, xb, z) FMA4(acc1, xb, w)
    }
    int rowA = row0 + r0;
    if (rowA < n) {
        float dv = dinv[rowA];
        ushort4 o;
        o.x = f2bf(acc0.x * dv); o.y = f2bf(acc0.y * dv);
        o.z = f2bf(acc0.z * dv); o.w = f2bf(acc0.w * dv);
        *((ushort4*)&hw16[(size_t)rowA * C_OUT + c0]) = o;
    }
    int rowB = row0 + r1;
    if (rowB < n) {
        float dv = dinv[rowB];
        ushort4 o;
        o.x = f2bf(acc1.x * dv); o.y = f2bf(acc1.y * dv);
        o.z = f2bf(acc1.z * dv); o.w = f2bf(acc1.w * dv);
        *((ushort4*)&hw16[(size_t)rowB * C_OUT + c0]) = o;
    }
}

// ================= block-staged aggregate: 16 nodes/block, lane owns channel =================
// out[v,c] = dinv[v] * (sum_s hw[s,c] + hw[v,c]) + bias[c]
// Block stages ptr[17] + the block's contiguous srcs range into LDS once (the
// ptr->srcs dependent-latency chain paid per 16 nodes, not per node). Each
// 32-lane group processes 2 nodes; lane c owns channel c -> NO cross-lane ops
// (R7 shfl hazard structurally impossible). Source ids come from LDS broadcast.
__global__ __launch_bounds__(256) void aggregate_kernel(const unsigned short* __restrict__ hw16,
                                                        const float* __restrict__ dinv,
                                                        const int* __restrict__ ptr,
                                                        const int* __restrict__ srcs,
                                                        const float* __restrict__ bias,
                                                        float* __restrict__ out, int n) {
    __shared__ int sids[ECAP];
    __shared__ int sptr[NPB + 1];
    int v0 = blockIdx.x * NPB;
    int tid = threadIdx.x;
    if (tid <= NPB) {
        int v = v0 + tid;
        sptr[tid] = ptr[v <= n ? v : n];
    }
    __syncthreads();
    int r0 = sptr[0];
    int cnt = sptr[NPB] - r0;
    if (cnt > ECAP) cnt = ECAP;           // overflow edges read direct from global
    for (int i = tid; i < cnt; i += 256) sids[i] = srcs[r0 + i];
    __syncthreads();

    int g = tid >> 5;   // group 0..7
    int c = tid & 31;   // owned channel
#pragma unroll
    for (int k = 0; k < NPB; k += 8) {
        int v = v0 + g + k;
        if (v < n) {
            int b = sptr[g + k] - r0;
            int e = sptr[g + k + 1] - r0;
            float a0 = 0.f, a1 = 0.f, a2 = 0.f, a3 = 0.f;
            int i = b;
            for (; i + 3 < e; i += 4) {
                int s0 = (i     < cnt) ? sids[i]     : srcs[r0 + i];
                int s1 = (i + 1 < cnt) ? sids[i + 1] : srcs[r0 + i + 1];
                int s2 = (i + 2 < cnt) ? sids[i + 2] : srcs[r0 + i + 2];
                int s3 = (i + 3 < cnt) ? sids[i + 3] : srcs[r0 + i + 3];
                a0 += bf2f(hw16[(size_t)s0 * C_OUT + c]);
                a1 += bf2f(hw16[(size_t)s1 * C_OUT + c]);
                a2 += bf2f(hw16[(size_t)s2 * C_OUT + c]);
                a3 += bf2f(hw16[(size_t)s3 * C_OUT + c]);
            }
            for (; i < e; ++i) {
                int s = (i < cnt) ? sids[i] : srcs[r0 + i];
                a0 += bf2f(hw16[(size_t)s * C_OUT + c]);
            }
            float dv = dinv[v];
            float acc = (a0 + a1) + (a2 + a3);
            out[(size_t)v * C_OUT + c] =
                dv * (acc + bf2f(hw16[(size_t)v * C_OUT + c])) + bias[c];
        }
    }
}

// ================= fallback (R1 atomic path) =================
__global__ void count_deg_kernel(const int* __restrict__ dst, int E, int* __restrict__ cnt) {
    int i = blockIdx.x * blockDim.x + threadIdx.x;
    if (i < E) atomicAdd(&cnt[dst[i]], 1);
}

__global__ void dinv_from_cnt_kernel(const int* __restrict__ cnt, float* __restrict__ dinv, int n) {
    int i = blockIdx.x * blockDim.x + threadIdx.x;
    if (i < n) dinv[i] = rsqrtf((float)(cnt[i] + 1));
}

__global__ void selfloop_bias_kernel(const float* __restrict__ h, const float* __restrict__ dinv,
                                     const float* __restrict__ b, float* __restrict__ out, int n) {
    int t = blockIdx.x * blockDim.x + threadIdx.x;
    if (t >= n * C_OUT) return;
    int i = t >> 5;
    int c = t & 31;
    float di = dinv[i];
    out[t] = h[t] * di * di + b[c];
}

__global__ void scatter_kernel(const int* __restrict__ src, const int* __restrict__ dst, int E,
                               const float* __restrict__ dinv, const float* __restrict__ h,
                               float* __restrict__ out) {
    int t = blockIdx.x * blockDim.x + threadIdx.x;
    int e = t >> 5;
    if (e >= E) return;
    int c = t & 31;
    int s = src[e];
    int d = dst[e];
    float norm = dinv[s] * dinv[d];
    float v = h[(size_t)s * C_OUT + c] * norm;
    atomicAdd(&out[(size_t)d * C_OUT + c], v);
}

// plain gemm (no dinv fold) for fallback
__global__ __launch_bounds__(256) void gemm1_plain_kernel(const float* __restrict__ x,
                                                          const float* __restrict__ W,
                                                          float* __restrict__ h, int n) {
    __shared__ float Ws[C_IN * C_OUT];
    for (int i = threadIdx.x; i < (C_IN * C_OUT) / 4; i += 256)
        ((float4*)Ws)[i] = ((const float4*)W)[i];
    __syncthreads();
    int t = blockIdx.x * 256 + threadIdx.x;
    int row = t >> 5;
    if (row >= n) return;
    int c = t & 31;
    const float4* xr = (const float4*)(x + (size_t)row * C_IN);
    float acc = 0.f;
#pragma unroll
    for (int k4 = 0; k4 < C_IN / 4; ++k4) {
        float4 xv = xr[k4];
        acc = fmaf(xv.x, Ws[(k4 * 4 + 0) * C_OUT + c], acc);
        acc = fmaf(xv.y, Ws[(k4 * 4 + 1) * C_OUT + c], acc);
        acc = fmaf(xv.z, Ws[(k4 * 4 + 2) * C_OUT + c], acc);
        acc = fmaf(xv.w, Ws[(k4 * 4 + 3) * C_OUT + c], acc);
    }
    h[(size_t)row * C_OUT + c] = acc;
}

__global__ __launch_bounds__(256) void gemm2_relu_plain_kernel(const float* __restrict__ a,
                                                               const float* __restrict__ W,
                                                               float* __restrict__ h, int n) {
    __shared__ float Ws[C_OUT * C_OUT];
    for (int i = threadIdx.x; i < (C_OUT * C_OUT) / 4; i += 256)
        ((float4*)Ws)[i] = ((const float4*)W)[i];
    __syncthreads();
    int t = blockIdx.x * 256 + threadIdx.x;
    int row = t >> 5;
    if (row >= n) return;
    int c = t & 31;
    const float4* ar = (const float4*)(a + (size_t)row * C_OUT);
    float acc = 0.f;
#pragma unroll
    for (int k4 = 0; k4 < C_OUT / 4; ++k4) {
        float4 av = ar[k4];
        acc = fmaf(fmaxf(av.x, 0.f), Ws[(k4 * 4 + 0) * C_OUT + c], acc);
        acc = fmaf(fmaxf(av.y, 0.f), Ws[(k4 * 4 + 1) * C_OUT + c], acc);
        acc = fmaf(fmaxf(av.z, 0.f), Ws[(k4 * 4 + 2) * C_OUT + c], acc);
        acc = fmaf(fmaxf(av.w, 0.f), Ws[(k4 * 4 + 3) * C_OUT + c], acc);
    }
    h[(size_t)row * C_OUT + c] = acc;
}

extern "C" void kernel_launch(void* const* d_in, const int* in_sizes, int n_in,
                              void* d_out, int out_size, void* d_ws, size_t ws_size,
                              hipStream_t stream) {
    const float* x  = (const float*)d_in[0];
    const int*   ei = (const int*)d_in[1];
    const float* W1 = (const float*)d_in[2];
    const float* b1 = (const float*)d_in[3];
    const float* W2 = (const float*)d_in[4];
    const float* b2 = (const float*)d_in[5];

    const int n = in_sizes[0] / C_IN;   // 100000
    const int E = in_sizes[1] / 2;      // 1600000
    const int* src = ei;
    const int* dst = ei + E;
    float* aout = (float*)d_out;

    const int nb = (n + BSZ - 1) >> BSH;            // 391
    const size_t MB = 1024 * 1024;
    char* ws = (char*)d_ws;

    size_t need = 16 * MB + (size_t)n * C_OUT * sizeof(unsigned short);

    if (ws_size >= need && n <= (MAXNB << BSH) && n < (1 << 24)) {
        int*            bcnt  = (int*)(ws + 0);
        int*            bbase = (int*)(ws + 64 * 1024);
        int*            gcur  = (int*)(ws + 128 * 1024);
        float*          dinv  = (float*)(ws + 192 * 1024);
        int*            ptr   = (int*)(ws + 704 * 1024);
        unsigned int*   pk    = (unsigned int*)(ws + 2 * MB);
        int*            srcs  = (int*)(ws + 9 * MB);
        unsigned short* hw16  = (unsigned short*)(ws + 16 * MB);  // n*32 bf16 = 6.4 MB

        // ---- build bucket-grouped pairs, then per-node CSR ----
        hipMemsetAsync(bcnt, 0, (size_t)(nb + 1) * sizeof(int), stream);
        bucket_hist_kernel<<<512, 256, 0, stream>>>(dst, E, bcnt, nb);
        bucket_scan_kernel<<<1, 512, 0, stream>>>(bcnt, bbase, gcur, nb, E);
        bin_kernel<<<(E + CH - 1) / CH, 256, 0, stream>>>(src, dst, E, gcur, pk, nb);
        csr_build_kernel<<<nb, 256, 0, stream>>>(pk, bbase, ptr, srcs, dinv, n, E);

        const int gb = (n + TR - 1) / TR;           // 1563
        const int ga = (n + NPB - 1) / NPB;         // 6250 aggregate blocks
        // ---- layer 1 ----
        gemm1_kernel<<<gb, 256, 0, stream>>>(x, W1, dinv, hw16, n);
        aggregate_kernel<<<ga, 256, 0, stream>>>(hw16, dinv, ptr, srcs, b1, aout, n);
        // ---- layer 2 ----
        gemm2_relu_kernel<<<gb, 256, 0, stream>>>(aout, W2, dinv, hw16, n);
        aggregate_kernel<<<ga, 256, 0, stream>>>(hw16, dinv, ptr, srcs, b2, aout, n);
    } else {
        // -------- fallback: R1 atomic path (needs ~13.6 MB) --------
        int*   cnt  = (int*)ws;
        float* dinv = (float*)(ws + 400000);
        float* h    = (float*)(ws + 800000);

        hipMemsetAsync(cnt, 0, (size_t)n * sizeof(int), stream);
        count_deg_kernel<<<(E + 255) / 256, 256, 0, stream>>>(dst, E, cnt);
        gemm1_plain_kernel<<<(n * C_OUT + 255) / 256, 256, 0, stream>>>(x, W1, h, n);
        dinv_from_cnt_kernel<<<(n + 255) / 256, 256, 0, stream>>>(cnt, dinv, n);
        selfloop_bias_kernel<<<(n * C_OUT + 255) / 256, 256, 0, stream>>>(h, dinv, b1, aout, n);
        scatter_kernel<<<((size_t)E * 32 + 255) / 256, 256, 0, stream>>>(src, dst, E, dinv, h, aout);
        gemm2_relu_plain_kernel<<<(n * C_OUT + 255) / 256, 256, 0, stream>>>(aout, W2, h, n);
        selfloop_bias_kernel<<<(n * C_OUT + 255) / 256, 256, 0, stream>>>(h, dinv, b2, aout, n);
        scatter_kernel<<<((size_t)E * 32 + 255) / 256, 256, 0, stream>>>(src, dst, E, dinv, h, aout);
    }
}

// Round 12
// 169.639 us; speedup vs baseline: 1.6985x; 1.0181x over previous
//
#include <hip/hip_runtime.h>
#include <hip/hip_bf16.h>

#define C_IN 128
#define C_OUT 32
#define BSH 8               // 256 nodes per dst-bucket
#define BSZ 256             // nodes per bucket
#define CH 8192             // edges per bin block
#define MAXNB 512           // LDS cap for bucket arrays (supports n <= 131072)
#define NHB 256             // histogram partial blocks (no memset, no global atomics)
#define TR 64               // gemm row-tile
#define NPB 16              // nodes per aggregate block
#define ECAP 1024           // LDS-staged edges per aggregate block (avg 256, P(>1024)~0)

static __device__ __forceinline__ unsigned short f2bf(float f) {
    __hip_bfloat16 h = __float2bfloat16(f);   // RTNE
    return *reinterpret_cast<unsigned short*>(&h);
}
static __device__ __forceinline__ float bf2f(unsigned short u) {
    unsigned int v = ((unsigned int)u) << 16;
    return __uint_as_float(v);
}

// ================= bucket histogram: per-block partials (no pre-zeroed global) =================
__global__ __launch_bounds__(256) void bucket_hist_kernel(const int* __restrict__ dst, int E,
                                                          int* __restrict__ part, int nb) {
    __shared__ int hcnt[MAXNB];
    for (int i = threadIdx.x; i < nb; i += 256) hcnt[i] = 0;
    __syncthreads();
    int stride = NHB * 256;
    for (int e = blockIdx.x * 256 + threadIdx.x; e < E; e += stride)
        atomicAdd(&hcnt[dst[e] >> BSH], 1);
    __syncthreads();
    for (int i = threadIdx.x; i < nb; i += 256)
        part[blockIdx.x * MAXNB + i] = hcnt[i];   // plain store, full row written
}

// ================= sum partials + bucket exclusive scan (1 block) =================
__global__ __launch_bounds__(512) void bucket_scan_kernel(const int* __restrict__ part,
                                                          int* __restrict__ bbase,
                                                          int* __restrict__ gcur, int nb, int E) {
    __shared__ int tmp[512];
    int v = 0;
    if (threadIdx.x < nb)
        for (int b = 0; b < NHB; ++b) v += part[b * MAXNB + threadIdx.x];  // coalesced across tid
    tmp[threadIdx.x] = v;
    __syncthreads();
    for (int off = 1; off < 512; off <<= 1) {
        int t = (threadIdx.x >= off) ? tmp[threadIdx.x - off] : 0;
        __syncthreads();
        tmp[threadIdx.x] += t;
        __syncthreads();
    }
    if (threadIdx.x < nb) {
        int ex = tmp[threadIdx.x] - v;
        bbase[threadIdx.x] = ex;
        gcur[threadIdx.x] = ex;
    }
    if (threadIdx.x == 0) bbase[nb] = E;
}

// ================= bin edges into bucket-grouped packed (src<<8 | dst&255) =================
__global__ __launch_bounds__(256) void bin_kernel(const int* __restrict__ src,
                                                  const int* __restrict__ dst, int E,
                                                  int* __restrict__ gcur,
                                                  unsigned int* __restrict__ pk, int nb) {
    __shared__ int lcnt[MAXNB];
    __shared__ int lbase[MAXNB];
    int e0 = blockIdx.x * CH;
    for (int i = threadIdx.x; i < nb; i += 256) lcnt[i] = 0;
    __syncthreads();
    for (int i = threadIdx.x; i < CH; i += 256) {
        int e = e0 + i;
        if (e < E) atomicAdd(&lcnt[dst[e] >> BSH], 1);
    }
    __syncthreads();
    for (int i = threadIdx.x; i < nb; i += 256) {
        int c = lcnt[i];
        lbase[i] = c ? atomicAdd(&gcur[i], c) : 0;
        lcnt[i] = 0;
    }
    __syncthreads();
    for (int i = threadIdx.x; i < CH; i += 256) {
        int e = e0 + i;
        if (e < E) {
            int d = dst[e], s = src[e];
            int b = d >> BSH;
            int off = atomicAdd(&lcnt[b], 1);
            pk[lbase[b] + off] = ((unsigned int)s << BSH) | (unsigned int)(d & (BSZ - 1));
        }
    }
}

// ================= per-bucket counting sort -> full CSR + dinv =================
__global__ __launch_bounds__(256) void csr_build_kernel(const unsigned int* __restrict__ pk,
                                                        const int* __restrict__ bbase,
                                                        int* __restrict__ ptr,
                                                        int* __restrict__ srcs,
                                                        float* __restrict__ dinv, int n, int E) {
    __shared__ int cnt[BSZ];
    __shared__ int tmp[BSZ];
    __shared__ int cur[BSZ];
    int b = blockIdx.x;
    int tid = threadIdx.x;
    int r0 = bbase[b], r1 = bbase[b + 1];
    cnt[tid] = 0;
    __syncthreads();
    for (int i = r0 + tid; i < r1; i += 256)
        atomicAdd(&cnt[pk[i] & (BSZ - 1)], 1);
    __syncthreads();
    int v = cnt[tid];
    tmp[tid] = v;
    __syncthreads();
    for (int off = 1; off < 256; off <<= 1) {
        int t = (tid >= off) ? tmp[tid - off] : 0;
        __syncthreads();
        tmp[tid] += t;
        __syncthreads();
    }
    int ex = tmp[tid] - v;  // exclusive offset within bucket
    cur[tid] = ex;
    int node = (b << BSH) + tid;
    if (node < n) {
        ptr[node] = r0 + ex;
        dinv[node] = rsqrtf((float)(v + 1));  // +1 self loop
    }
    if (b == 0 && tid == 0) ptr[n] = E;
    __syncthreads();
    for (int i = r0 + tid; i < r1; i += 256) {
        unsigned int u = pk[i];
        int d = u & (BSZ - 1);
        int pos = r0 + atomicAdd(&cur[d], 1);
        srcs[pos] = (int)(u >> BSH);
    }
}

// 4 chained FMAs: acc.comp += dot(xv, W[k..k+3][c_comp])
#define FMA4(acc, xv, comp)                           \
    acc.comp = fmaf(xv.x, w0.comp, acc.comp);         \
    acc.comp = fmaf(xv.y, w1.comp, acc.comp);         \
    acc.comp = fmaf(xv.z, w2.comp, acc.comp);         \
    acc.comp = fmaf(xv.w, w3.comp, acc.comp);

// ================= GEMM1 (tiled) + dinv fold: hw16 = bf16((x @ W1) * dinv[row]) =================
// unroll capped at 2 (R5: full unroll -> 256 VGPR + scratch spill). 3 blk/CU.
__global__ __launch_bounds__(256, 3) void gemm1_kernel(const float* __restrict__ x,
                                                       const float* __restrict__ W,
                                                       const float* __restrict__ dinv,
                                                       unsigned short* __restrict__ hw16, int n) {
    __shared__ float xs[TR][C_IN + 4];   // 64 x 132 = 33 KB (pad -> 2-way max aliasing)
    __shared__ float Ws[C_IN * C_OUT];   // 16 KB
    int tid = threadIdx.x;
    for (int i = tid; i < (C_IN * C_OUT) / 4; i += 256)
        ((float4*)Ws)[i] = ((const float4*)W)[i];
    int row0 = blockIdx.x * TR;
    for (int i = tid; i < TR * (C_IN / 4); i += 256) {
        int r = i >> 5, k4 = i & 31;
        int row = row0 + r;
        float4 v = make_float4(0.f, 0.f, 0.f, 0.f);
        if (row < n) v = ((const float4*)(x + (size_t)row * C_IN))[k4];
        *((float4*)&xs[r][k4 * 4]) = v;
    }
    __syncthreads();

    int rp = tid >> 3;          // 0..31 -> rows 2rp, 2rp+1
    int c0 = (tid & 7) * 4;     // channel group
    int r0 = rp * 2, r1 = r0 + 1;
    float4 acc0 = make_float4(0.f, 0.f, 0.f, 0.f);
    float4 acc1 = make_float4(0.f, 0.f, 0.f, 0.f);
#pragma unroll 2
    for (int k4 = 0; k4 < C_IN / 4; ++k4) {
        float4 xa = *((const float4*)&xs[r0][k4 * 4]);
        float4 xb = *((const float4*)&xs[r1][k4 * 4]);
        float4 w0 = *((const float4*)&Ws[(k4 * 4 + 0) * C_OUT + c0]);
        float4 w1 = *((const float4*)&Ws[(k4 * 4 + 1) * C_OUT + c0]);
        float4 w2 = *((const float4*)&Ws[(k4 * 4 + 2) * C_OUT + c0]);
        float4 w3 = *((const float4*)&Ws[(k4 * 4 + 3) * C_OUT + c0]);
        FMA4(acc0, xa, x) FMA4(acc0, xa, y) FMA4(acc0, xa, z) FMA4(acc0, xa, w)
        FMA4(acc1, xb, x) FMA4(acc1, xb, y) FMA4(acc1, xb, z) FMA4(acc1, xb, w)
    }
    int rowA = row0 + r0;
    if (rowA < n) {
        float dv = dinv[rowA];
        ushort4 o;
        o.x = f2bf(acc0.x * dv); o.y = f2bf(acc0.y * dv);
        o.z = f2bf(acc0.z * dv); o.w = f2bf(acc0.w * dv);
        *((ushort4*)&hw16[(size_t)rowA * C_OUT + c0]) = o;
    }
    int rowB = row0 + r1;
    if (rowB < n) {
        float dv = dinv[rowB];
        ushort4 o;
        o.x = f2bf(acc1.x * dv); o.y = f2bf(acc1.y * dv);
        o.z = f2bf(acc1.z * dv); o.w = f2bf(acc1.w * dv);
        *((ushort4*)&hw16[(size_t)rowB * C_OUT + c0]) = o;
    }
}

// ================= GEMM2 (tiled) + relu on load + dinv fold -> bf16 =================
__global__ __launch_bounds__(256, 4) void gemm2_relu_kernel(const float* __restrict__ a,
                                                            const float* __restrict__ W,
                                                            const float* __restrict__ dinv,
                                                            unsigned short* __restrict__ hw16, int n) {
    __shared__ float xs[TR][C_OUT + 4];  // 64 x 36 = 9 KB
    __shared__ float Ws[C_OUT * C_OUT];  // 4 KB
    int tid = threadIdx.x;
    for (int i = tid; i < (C_OUT * C_OUT) / 4; i += 256)
        ((float4*)Ws)[i] = ((const float4*)W)[i];
    int row0 = blockIdx.x * TR;
    for (int i = tid; i < TR * (C_OUT / 4); i += 256) {
        int r = i >> 3, k4 = i & 7;
        int row = row0 + r;
        float4 v = make_float4(0.f, 0.f, 0.f, 0.f);
        if (row < n) {
            v = ((const float4*)(a + (size_t)row * C_OUT))[k4];
            v.x = fmaxf(v.x, 0.f); v.y = fmaxf(v.y, 0.f);
            v.z = fmaxf(v.z, 0.f); v.w = fmaxf(v.w, 0.f);
        }
        *((float4*)&xs[r][k4 * 4]) = v;
    }
    __syncthreads();

    int rp = tid >> 3;
    int c0 = (tid & 7) * 4;
    int r0 = rp * 2, r1 = r0 + 1;
    float4 acc0 = make_float4(0.f, 0.f, 0.f, 0.f);
    float4 acc1 = make_float4(0.f, 0.f, 0.f, 0.f);
#pragma unroll 2
    for (int k4 = 0; k4 < C_OUT / 4; ++k4) {
        float4 xa = *((const float4*)&xs[r0][k4 * 4]);
        float4 xb = *((const float4*)&xs[r1][k4 * 4]);
        float4 w0 = *((const float4*)&Ws[(k4 * 4 + 0) * C_OUT + c0]);
        float4 w1 = *((const float4*)&Ws[(k4 * 4 + 1) * C_OUT + c0]);
        float4 w2 = *((const float4*)&Ws[(k4 * 4 + 2) * C_OUT + c0]);
        float4 w3 = *((const float4*)&Ws[(k4 * 4 + 3) * C_OUT + c0]);
        FMA4(acc0, xa, x) FMA4(acc0, xa, y) FMA4(acc0, xa, z) FMA4(acc0, xa, w)
        FMA4(acc1, xb, x) FMA4(acc1, xb, y) FMA4(acc1, xb, z) FMA4(acc1, xb, w)
    }
    int rowA = row0 + r0;
    if (rowA < n) {
        float dv = dinv[rowA];
        ushort4 o;
        o.x = f2bf(acc0.x * dv); o.y = f2bf(acc0.y * dv);
        o.z = f2bf(acc0.z * dv); o.w = f2bf(acc0.w * dv);
        *((ushort4*)&hw16[(size_t)rowA * C_OUT + c0]) = o;
    }
    int rowB = row0 + r1;
    if (rowB < n) {
        float dv = dinv[rowB];
        ushort4 o;
        o.x = f2bf(acc1.x * dv); o.y = f2bf(acc1.y * dv);
        o.z = f2bf(acc1.z * dv); o.w = f2bf(acc1.w * dv);
        *((ushort4*)&hw16[(size_t)rowB * C_OUT + c0]) = o;
    }
}

// ================= block-staged aggregate: 16 nodes/block, lane owns channel =================
// out[v,c] = dinv[v] * (sum_s hw[s,c] + hw[v,c]) + bias[c]
// Block stages ptr[17] + the block's contiguous srcs range into LDS once (the
// ptr->srcs dependent-latency chain paid per 16 nodes, not per node). Each
// 32-lane group processes 2 nodes; lane c owns channel c -> NO cross-lane ops
// (R7 shfl hazard structurally impossible). Source ids come from LDS broadcast.
__global__ __launch_bounds__(256) void aggregate_kernel(const unsigned short* __restrict__ hw16,
                                                        const float* __restrict__ dinv,
                                                        const int* __restrict__ ptr,
                                                        const int* __restrict__ srcs,
                                                        const float* __restrict__ bias,
                                                        float* __restrict__ out, int n) {
    __shared__ int sids[ECAP];
    __shared__ int sptr[NPB + 1];
    int v0 = blockIdx.x * NPB;
    int tid = threadIdx.x;
    if (tid <= NPB) {
        int v = v0 + tid;
        sptr[tid] = ptr[v <= n ? v : n];
    }
    __syncthreads();
    int r0 = sptr[0];
    int cnt = sptr[NPB] - r0;
    if (cnt > ECAP) cnt = ECAP;           // overflow edges read direct from global
    for (int i = tid; i < cnt; i += 256) sids[i] = srcs[r0 + i];
    __syncthreads();

    int g = tid >> 5;   // group 0..7
    int c = tid & 31;   // owned channel
#pragma unroll
    for (int k = 0; k < NPB; k += 8) {
        int v = v0 + g + k;
        if (v < n) {
            int b = sptr[g + k] - r0;
            int e = sptr[g + k + 1] - r0;
            float a0 = 0.f, a1 = 0.f, a2 = 0.f, a3 = 0.f;
            int i = b;
            for (; i + 3 < e; i += 4) {
                int s0 = (i     < cnt) ? sids[i]     : srcs[r0 + i];
                int s1 = (i + 1 < cnt) ? sids[i + 1] : srcs[r0 + i + 1];
                int s2 = (i + 2 < cnt) ? sids[i + 2] : srcs[r0 + i + 2];
                int s3 = (i + 3 < cnt) ? sids[i + 3] : srcs[r0 + i + 3];
                a0 += bf2f(hw16[(size_t)s0 * C_OUT + c]);
                a1 += bf2f(hw16[(size_t)s1 * C_OUT + c]);
                a2 += bf2f(hw16[(size_t)s2 * C_OUT + c]);
                a3 += bf2f(hw16[(size_t)s3 * C_OUT + c]);
            }
            for (; i < e; ++i) {
                int s = (i < cnt) ? sids[i] : srcs[r0 + i];
                a0 += bf2f(hw16[(size_t)s * C_OUT + c]);
            }
            float dv = dinv[v];
            float acc = (a0 + a1) + (a2 + a3);
            out[(size_t)v * C_OUT + c] =
                dv * (acc + bf2f(hw16[(size_t)v * C_OUT + c])) + bias[c];
        }
    }
}

// ================= fallback (R1 atomic path) =================
__global__ void count_deg_kernel(const int* __restrict__ dst, int E, int* __restrict__ cnt) {
    int i = blockIdx.x * blockDim.x + threadIdx.x;
    if (i < E) atomicAdd(&cnt[dst[i]], 1);
}

__global__ void dinv_from_cnt_kernel(const int* __restrict__ cnt, float* __restrict__ dinv, int n) {
    int i = blockIdx.x * blockDim.x + threadIdx.x;
    if (i < n) dinv[i] = rsqrtf((float)(cnt[i] + 1));
}

__global__ void selfloop_bias_kernel(const float* __restrict__ h, const float* __restrict__ dinv,
                                     const float* __restrict__ b, float* __restrict__ out, int n) {
    int t = blockIdx.x * blockDim.x + threadIdx.x;
    if (t >= n * C_OUT) return;
    int i = t >> 5;
    int c = t & 31;
    float di = dinv[i];
    out[t] = h[t] * di * di + b[c];
}

__global__ void scatter_kernel(const int* __restrict__ src, const int* __restrict__ dst, int E,
                               const float* __restrict__ dinv, const float* __restrict__ h,
                               float* __restrict__ out) {
    int t = blockIdx.x * blockDim.x + threadIdx.x;
    int e = t >> 5;
    if (e >= E) return;
    int c = t & 31;
    int s = src[e];
    int d = dst[e];
    float norm = dinv[s] * dinv[d];
    float v = h[(size_t)s * C_OUT + c] * norm;
    atomicAdd(&out[(size_t)d * C_OUT + c], v);
}

// plain gemm (no dinv fold) for fallback
__global__ __launch_bounds__(256) void gemm1_plain_kernel(const float* __restrict__ x,
                                                          const float* __restrict__ W,
                                                          float* __restrict__ h, int n) {
    __shared__ float Ws[C_IN * C_OUT];
    for (int i = threadIdx.x; i < (C_IN * C_OUT) / 4; i += 256)
        ((float4*)Ws)[i] = ((const float4*)W)[i];
    __syncthreads();
    int t = blockIdx.x * 256 + threadIdx.x;
    int row = t >> 5;
    if (row >= n) return;
    int c = t & 31;
    const float4* xr = (const float4*)(x + (size_t)row * C_IN);
    float acc = 0.f;
#pragma unroll
    for (int k4 = 0; k4 < C_IN / 4; ++k4) {
        float4 xv = xr[k4];
        acc = fmaf(xv.x, Ws[(k4 * 4 + 0) * C_OUT + c], acc);
        acc = fmaf(xv.y, Ws[(k4 * 4 + 1) * C_OUT + c], acc);
        acc = fmaf(xv.z, Ws[(k4 * 4 + 2) * C_OUT + c], acc);
        acc = fmaf(xv.w, Ws[(k4 * 4 + 3) * C_OUT + c], acc);
    }
    h[(size_t)row * C_OUT + c] = acc;
}

__global__ __launch_bounds__(256) void gemm2_relu_plain_kernel(const float* __restrict__ a,
                                                               const float* __restrict__ W,
                                                               float* __restrict__ h, int n) {
    __shared__ float Ws[C_OUT * C_OUT];
    for (int i = threadIdx.x; i < (C_OUT * C_OUT) / 4; i += 256)
        ((float4*)Ws)[i] = ((const float4*)W)[i];
    __syncthreads();
    int t = blockIdx.x * 256 + threadIdx.x;
    int row = t >> 5;
    if (row >= n) return;
    int c = t & 31;
    const float4* ar = (const float4*)(a + (size_t)row * C_OUT);
    float acc = 0.f;
#pragma unroll
    for (int k4 = 0; k4 < C_OUT / 4; ++k4) {
        float4 av = ar[k4];
        acc = fmaf(fmaxf(av.x, 0.f), Ws[(k4 * 4 + 0) * C_OUT + c], acc);
        acc = fmaf(fmaxf(av.y, 0.f), Ws[(k4 * 4 + 1) * C_OUT + c], acc);
        acc = fmaf(fmaxf(av.z, 0.f), Ws[(k4 * 4 + 2) * C_OUT + c], acc);
        acc = fmaf(fmaxf(av.w, 0.f), Ws[(k4 * 4 + 3) * C_OUT + c], acc);
    }
    h[(size_t)row * C_OUT + c] = acc;
}

extern "C" void kernel_launch(void* const* d_in, const int* in_sizes, int n_in,
                              void* d_out, int out_size, void* d_ws, size_t ws_size,
                              hipStream_t stream) {
    const float* x  = (const float*)d_in[0];
    const int*   ei = (const int*)d_in[1];
    const float* W1 = (const float*)d_in[2];
    const float* b1 = (const float*)d_in[3];
    const float* W2 = (const float*)d_in[4];
    const float* b2 = (const float*)d_in[5];

    const int n = in_sizes[0] / C_IN;   // 100000
    const int E = in_sizes[1] / 2;      // 1600000
    const int* src = ei;
    const int* dst = ei + E;
    float* aout = (float*)d_out;

    const int nb = (n + BSZ - 1) >> BSH;            // 391
    const size_t MB = 1024 * 1024;
    char* ws = (char*)d_ws;

    size_t need = 16 * MB + (size_t)n * C_OUT * sizeof(unsigned short);

    if (ws_size >= need && n <= (MAXNB << BSH) && n < (1 << 24)) {
        // layout: part 0..512K | bbase 512K | gcur 576K | dinv 640K..1040K |
        //         ptr 1040K..1440K | pk 2M..8.4M | srcs 9M..15.4M | hw16 16M..22.4M
        int*            part  = (int*)(ws + 0);                  // NHB*MAXNB ints = 512 KB
        int*            bbase = (int*)(ws + 512 * 1024);
        int*            gcur  = (int*)(ws + 576 * 1024);
        float*          dinv  = (float*)(ws + 640 * 1024);
        int*            ptr   = (int*)(ws + 1040 * 1024);
        unsigned int*   pk    = (unsigned int*)(ws + 2 * MB);
        int*            srcs  = (int*)(ws + 9 * MB);
        unsigned short* hw16  = (unsigned short*)(ws + 16 * MB); // n*32 bf16 = 6.4 MB

        // ---- build bucket-grouped pairs, then per-node CSR (NO memset node in graph) ----
        bucket_hist_kernel<<<NHB, 256, 0, stream>>>(dst, E, part, nb);
        bucket_scan_kernel<<<1, 512, 0, stream>>>(part, bbase, gcur, nb, E);
        bin_kernel<<<(E + CH - 1) / CH, 256, 0, stream>>>(src, dst, E, gcur, pk, nb);
        csr_build_kernel<<<nb, 256, 0, stream>>>(pk, bbase, ptr, srcs, dinv, n, E);

        const int gb = (n + TR - 1) / TR;           // 1563
        const int ga = (n + NPB - 1) / NPB;         // 6250 aggregate blocks
        // ---- layer 1 ----
        gemm1_kernel<<<gb, 256, 0, stream>>>(x, W1, dinv, hw16, n);
        aggregate_kernel<<<ga, 256, 0, stream>>>(hw16, dinv, ptr, srcs, b1, aout, n);
        // ---- layer 2 ----
        gemm2_relu_kernel<<<gb, 256, 0, stream>>>(aout, W2, dinv, hw16, n);
        aggregate_kernel<<<ga, 256, 0, stream>>>(hw16, dinv, ptr, srcs, b2, aout, n);
    } else {
        // -------- fallback: R1 atomic path (needs ~13.6 MB) --------
        int*   cnt  = (int*)ws;
        float* dinv = (float*)(ws + 400000);
        float* h    = (float*)(ws + 800000);

        hipMemsetAsync(cnt, 0, (size_t)n * sizeof(int), stream);
        count_deg_kernel<<<(E + 255) / 256, 256, 0, stream>>>(dst, E, cnt);
        gemm1_plain_kernel<<<(n * C_OUT + 255) / 256, 256, 0, stream>>>(x, W1, h, n);
        dinv_from_cnt_kernel<<<(n + 255) / 256, 256, 0, stream>>>(cnt, dinv, n);
        selfloop_bias_kernel<<<(n * C_OUT + 255) / 256, 256, 0, stream>>>(h, dinv, b1, aout, n);
        scatter_kernel<<<((size_t)E * 32 + 255) / 256, 256, 0, stream>>>(src, dst, E, dinv, h, aout);
        gemm2_relu_plain_kernel<<<(n * C_OUT + 255) / 256, 256, 0, stream>>>(aout, W2, h, n);
        selfloop_bias_kernel<<<(n * C_OUT + 255) / 256, 256, 0, stream>>>(h, dinv, b2, aout, n);
        scatter_kernel<<<((size_t)E * 32 + 255) / 256, 256, 0, stream>>>(src, dst, E, dinv, h, aout);
    }
}